// Round 3
// baseline (128.436 us; speedup 1.0000x reference)
//
#include <hip/hip_runtime.h>

// NCC loss, fused single-pass. Round 3: vertical-first separable box sums.
//  - Each thread owns 4 columns; keeps 5 vertical running sums (I,J,I2,J2,IJ)
//    over the 9-row window, updated with 1 add-row + 1 sub-row per output row
//    (2 float4 loads per input per row; sub-row is an L2 hit).
//  - Horizontal 9-sum done ONCE per output row on the vertical sums, via
//    per-thread prefix sums (float4 per quantity) exchanged through
//    double-buffered LDS (1 barrier/row):
//      h[c] = (L.p3 - L.p_{c-1}) + own.p3 + R.p_c
//  - cc divide via v_rcp_f32 (__builtin_amdgcn_rcpf), ~1e-7 rel err.
// R2 profile: VALU-busy 24us at 57%, occupancy 30% -> cut ops ~2x.

#define W 512
#define H 512
#define BH 8
#define NBANDS (H / BH)      // 64
#define NT 128               // 4 columns per thread -> 512 columns

__device__ __forceinline__ float4 ld4(const float* p) {
    return *reinterpret_cast<const float4*>(p);
}

__global__ __launch_bounds__(NT)
void ncc_main(const float* __restrict__ I, const float* __restrict__ J,
              float* __restrict__ partials) {
    const int blk  = blockIdx.x;
    const int b    = blk / NBANDS;
    const int band = blk % NBANDS;
    const int y0   = band * BH;
    const float* Ip = I + (size_t)b * (H * W);
    const float* Jp = J + (size_t)b * (H * W);
    const int tid = threadIdx.x;
    const int x0  = tid * 4;

    // Prefix-exchange buffers: [parity][quantity][slot]; slots 0 and NT+1 are
    // permanent zeros (image-edge horizontal padding).
    __shared__ float4 xch[2][5][NT + 2];
    if (tid < 4) {
        int p = tid & 1, s = (tid >> 1) * (NT + 1);   // slots 0 and NT+1
        #pragma unroll
        for (int q = 0; q < 5; ++q)
            xch[p][q][s] = make_float4(0.f, 0.f, 0.f, 0.f);
    }

    // Vertical running sums over the current 9-row window, own 4 columns.
    float v[5][4];
    #pragma unroll
    for (int q = 0; q < 5; ++q)
        #pragma unroll
        for (int c = 0; c < 4; ++c) v[q][c] = 0.f;

    auto vadd = [&](int row) {
        float4 a = ld4(Ip + row * W + x0);
        float4 bb = ld4(Jp + row * W + x0);
        float av[4] = {a.x, a.y, a.z, a.w};
        float bv[4] = {bb.x, bb.y, bb.z, bb.w};
        #pragma unroll
        for (int c = 0; c < 4; ++c) {
            v[0][c] += av[c];
            v[1][c] += bv[c];
            v[2][c] += av[c] * av[c];
            v[3][c] += bv[c] * bv[c];
            v[4][c] += av[c] * bv[c];
        }
    };
    auto vsub = [&](int row) {
        float4 a = ld4(Ip + row * W + x0);
        float4 bb = ld4(Jp + row * W + x0);
        float av[4] = {a.x, a.y, a.z, a.w};
        float bv[4] = {bb.x, bb.y, bb.z, bb.w};
        #pragma unroll
        for (int c = 0; c < 4; ++c) {
            v[0][c] -= av[c];
            v[1][c] -= bv[c];
            v[2][c] -= av[c] * av[c];
            v[3][c] -= bv[c] * bv[c];
            v[4][c] -= av[c] * bv[c];
        }
    };

    // Prime with rows y0-4 .. y0+3 (y0+3 <= 507 < H always; only low clip).
    #pragma unroll
    for (int dr = -4; dr < 4; ++dr) {
        int r = y0 + dr;
        if (r >= 0) vadd(r);
    }

    float cc_acc = 0.f;
    const float inv81 = 1.f / 81.f;
    #pragma unroll
    for (int i = 0; i < BH; ++i) {
        const int y = y0 + i;
        const int p = i & 1;
        if (y + 4 < H) vadd(y + 4);   // window -> rows [y-4, y+4] clipped

        // Per-quantity prefix sums over own 4 columns, packed as float4.
        float4 pre[5];
        #pragma unroll
        for (int q = 0; q < 5; ++q) {
            float4 pr;
            pr.x = v[q][0];
            pr.y = pr.x + v[q][1];
            pr.z = pr.y + v[q][2];
            pr.w = pr.z + v[q][3];
            pre[q] = pr;
            xch[p][q][tid + 1] = pr;
        }
        __syncthreads();

        float h[5][4];
        #pragma unroll
        for (int q = 0; q < 5; ++q) {
            float4 L = xch[p][q][tid];
            float4 R = xch[p][q][tid + 2];
            float base = L.w + pre[q].w;
            h[q][0] = base + R.x;
            h[q][1] = (base - L.x) + R.y;
            h[q][2] = (base - L.y) + R.z;
            h[q][3] = (base - L.z) + R.w;
        }

        #pragma unroll
        for (int c = 0; c < 4; ++c) {
            float Is = h[0][c], Js = h[1][c];
            float I2 = h[2][c], J2 = h[3][c], IJ = h[4][c];
            float cross = IJ - Is * Js * inv81;
            float Ivar  = I2 - Is * Is * inv81;
            float Jvar  = J2 - Js * Js * inv81;
            cc_acc += cross * cross * __builtin_amdgcn_rcpf(Ivar * Jvar + 1e-6f);
        }

        if (y - 4 >= 0) vsub(y - 4);  // drop row y-4 for next iteration
    }

    // Block reduction: 2 waves.
    #pragma unroll
    for (int off = 32; off > 0; off >>= 1)
        cc_acc += __shfl_down(cc_acc, off, 64);
    __shared__ float wsum[NT / 64];
    if ((tid & 63) == 0) wsum[tid >> 6] = cc_acc;
    __syncthreads();
    if (tid == 0) partials[blockIdx.x] = wsum[0] + wsum[1];
}

__global__ __launch_bounds__(256)
void ncc_finish(const float* __restrict__ partials, float* __restrict__ out,
                int n, float inv_total) {
    float v = 0.f;
    for (int i = threadIdx.x; i < n; i += blockDim.x) v += partials[i];
    #pragma unroll
    for (int off = 32; off > 0; off >>= 1)
        v += __shfl_down(v, off, 64);
    __shared__ float wsum[4];
    if ((threadIdx.x & 63) == 0) wsum[threadIdx.x >> 6] = v;
    __syncthreads();
    if (threadIdx.x == 0) {
        float t = wsum[0] + wsum[1] + wsum[2] + wsum[3];
        out[0] = 1.0f - t * inv_total;
    }
}

extern "C" void kernel_launch(void* const* d_in, const int* in_sizes, int n_in,
                              void* d_out, int out_size, void* d_ws, size_t ws_size,
                              hipStream_t stream) {
    const float* I = (const float*)d_in[0];   // predict
    const float* J = (const float*)d_in[1];   // target
    float* out = (float*)d_out;
    float* partials = (float*)d_ws;           // nblocks floats (8 KB)

    const int n = in_sizes[0];                // B*1*H*W
    const int B = n / (H * W);
    const int nblocks = B * NBANDS;

    ncc_main<<<nblocks, NT, 0, stream>>>(I, J, partials);
    ncc_finish<<<1, 256, 0, stream>>>(partials, out, nblocks, 1.0f / (float)n);
}